// Round 4
// baseline (509.557 us; speedup 1.0000x reference)
//
#include <hip/hip_runtime.h>
#include <math.h>

#define BB    128
#define TT    1024
#define RNN   1024
#define EMBD  512
#define ATTD  128
#define NFILT 32
#define KSZ   31
#define PADK  15
#define CK    62      // 2 * 31
#define SPLIT 16
#define ETILE 128

// fast tanh: t = exp(-2|x|); r = (1-t)/(1+t); sign-restore.
// |err| ~ 1e-6 absolute, saturates correctly, no overflow/NaN for any finite x.
__device__ __forceinline__ float fast_tanhf(float x) {
  const float ax = fabsf(x);
  const float t  = __expf(-2.f * ax);
  const float r  = (1.f - t) / (1.f + t);
  return copysignf(r, x);
}

// ---------------- K1 (fused): blocks [0,128) -> pq = hidden @ w_query
//                              blocks [128,159) -> WL[ck][a] = sum_f wconv[f][ck]*wloc[f][a]
__global__ __launch_bounds__(256) void k_pq_wl(const float* __restrict__ hid,
                                               const float* __restrict__ wq,
                                               const float* __restrict__ wconv,
                                               const float* __restrict__ wloc,
                                               float* __restrict__ pq,
                                               float* __restrict__ wl) {
  const int tid = threadIdx.x;
  if (blockIdx.x < BB) {
    const int b  = blockIdx.x;
    const int a  = tid & (ATTD - 1);
    const int kh = tid >> 7;                 // split-K half: 0 or 1
    __shared__ float sh[RNN];
    __shared__ float sred[ATTD];
    for (int i = tid; i < RNN; i += 256) sh[i] = hid[(size_t)b * RNN + i];
    __syncthreads();
    float acc = 0.f;
    const int k0 = kh * (RNN / 2);
    #pragma unroll 8
    for (int k = 0; k < RNN / 2; ++k)
      acc = fmaf(sh[k0 + k], wq[(size_t)(k0 + k) * ATTD + a], acc);
    if (kh == 1) sred[a] = acc;
    __syncthreads();
    if (kh == 0) pq[(size_t)b * ATTD + a] = acc + sred[a];
  } else {
    const int idx = (blockIdx.x - BB) * 256 + tid;   // 31*256 == 7936 == CK*ATTD
    const int ck = idx >> 7;
    const int a  = idx & (ATTD - 1);
    float acc = 0.f;
    #pragma unroll
    for (int f = 0; f < NFILT; ++f)
      acc = fmaf(wconv[f * CK + ck], wloc[f * ATTD + a], acc);
    wl[idx] = acc;
  }
}

// ---------------- K2: energies[b][t] = v . tanh(pq + loc + pmem), +mask
// One wave per t (iterated); lane holds a-pair (2*lane, 2*lane+1).
__global__ __launch_bounds__(256) void k_energy(
    const float* __restrict__ awc,   // [B,2,T]
    const float* __restrict__ pmem,  // [B,T,128]
    const float* __restrict__ wl,    // [62,128]
    const float* __restrict__ vvec,  // [128]
    const float* __restrict__ pq,    // [B,128]
    const unsigned char* __restrict__ mask, // [B,T] (bool bytes)
    float* __restrict__ en)          // [B,T] (raw energies)
{
  const int b  = blockIdx.x;
  const int t0 = blockIdx.y * ETILE;
  const int tid = threadIdx.x;
  __shared__ float s_aw[2][ETILE + 30];
  // stage attention_weights_cat with conv halo, zero-padded at borders
  for (int i = tid; i < 2 * (ETILE + 30); i += 256) {
    const int c = (i < ETILE + 30) ? 0 : 1;
    const int j = c ? (i - (ETILE + 30)) : i;
    const int tg = t0 - PADK + j;
    s_aw[c][j] = (tg >= 0 && tg < TT) ? awc[((size_t)b * 2 + c) * TT + tg] : 0.f;
  }
  __syncthreads();

  const int lane = tid & 63;
  const int wave = tid >> 6;
  // this lane's two WL columns, held in VGPRs for the whole tile
  float2 wlr[CK];
  const float2* wl2 = (const float2*)wl;
  #pragma unroll
  for (int ck = 0; ck < CK; ++ck) wlr[ck] = wl2[ck * 64 + lane];
  const float2 pq2 = ((const float2*)(pq + (size_t)b * ATTD))[lane];
  const float2 v2  = ((const float2*)vvec)[lane];
  const float2* pm2 = (const float2*)(pmem + (size_t)b * TT * ATTD);

  const int tbase = wave * (ETILE / 4);      // 32 consecutive t's per wave
  float2 pm_next = pm2[(size_t)(t0 + tbase) * 64 + lane];
  #pragma unroll 2
  for (int i = 0; i < ETILE / 4; ++i) {
    const int tl = tbase + i;                // local t within tile
    const int tg = t0 + tl;                  // global t
    const float2 pm = pm_next;
    if (i + 1 < ETILE / 4)
      pm_next = pm2[(size_t)(tg + 1) * 64 + lane];
    float x0 = pq2.x + pm.x;
    float x1 = pq2.y + pm.y;
    #pragma unroll
    for (int k = 0; k < KSZ; ++k) {          // channel 0
      const float a0 = s_aw[0][tl + k];
      x0 = fmaf(a0, wlr[k].x, x0);
      x1 = fmaf(a0, wlr[k].y, x1);
    }
    #pragma unroll
    for (int k = 0; k < KSZ; ++k) {          // channel 1
      const float a1 = s_aw[1][tl + k];
      x0 = fmaf(a1, wlr[KSZ + k].x, x0);
      x1 = fmaf(a1, wlr[KSZ + k].y, x1);
    }
    float e = v2.x * fast_tanhf(x0) + v2.y * fast_tanhf(x1);
    #pragma unroll
    for (int off = 32; off; off >>= 1) e += __shfl_xor(e, off);
    if (lane == 0)
      en[(size_t)b * TT + tg] = mask[(size_t)b * TT + tg] ? -INFINITY : e;
  }
}

// ---------------- K3: softmax over T, in place (energies -> weights)
__global__ __launch_bounds__(256) void k_softmax(float* __restrict__ w) {
  const int b = blockIdx.x;
  const int tid = threadIdx.x;
  const int lane = tid & 63, wave = tid >> 6;
  __shared__ float red[8];
  float4* w4 = (float4*)(w + (size_t)b * TT);
  float4 e = w4[tid];                          // 256 threads * 4 = 1024
  float m = fmaxf(fmaxf(e.x, e.y), fmaxf(e.z, e.w));
  #pragma unroll
  for (int off = 32; off; off >>= 1) m = fmaxf(m, __shfl_xor(m, off));
  if (lane == 0) red[wave] = m;
  __syncthreads();
  m = fmaxf(fmaxf(red[0], red[1]), fmaxf(red[2], red[3]));
  float4 p;
  p.x = expf(e.x - m); p.y = expf(e.y - m);
  p.z = expf(e.z - m); p.w = expf(e.w - m);
  float s = p.x + p.y + p.z + p.w;
  #pragma unroll
  for (int off = 32; off; off >>= 1) s += __shfl_xor(s, off);
  if (lane == 0) red[4 + wave] = s;
  __syncthreads();
  const float inv = 1.f / (red[4] + red[5] + red[6] + red[7]);
  p.x *= inv; p.y *= inv; p.z *= inv; p.w *= inv;
  w4[tid] = p;
}

// ---------------- K4: context partials over T-splits (the 256 MB stream)
__global__ __launch_bounds__(128) void k_ctx_part(const float* __restrict__ wts,
                                                  const float* __restrict__ mem,
                                                  float* __restrict__ part) {
  const int b = blockIdx.x, s = blockIdx.y, tid = threadIdx.x;
  const float4* m4 = (const float4*)(mem + (size_t)b * TT * EMBD);
  const int tbeg = s * (TT / SPLIT);
  const float4* w4 = (const float4*)(wts + (size_t)b * TT + tbeg);
  float4 acc = make_float4(0.f, 0.f, 0.f, 0.f);
  for (int i4 = 0; i4 < TT / SPLIT / 4; ++i4) {
    const float4 wv = w4[i4];                  // 4 weights, broadcast load
    #pragma unroll 4
    for (int j = 0; j < 4; ++j) {
      const int t = tbeg + i4 * 4 + j;
      const float w = (j == 0) ? wv.x : (j == 1) ? wv.y : (j == 2) ? wv.z : wv.w;
      const float4 mv = m4[(size_t)t * (EMBD / 4) + tid];
      acc.x = fmaf(w, mv.x, acc.x);
      acc.y = fmaf(w, mv.y, acc.y);
      acc.z = fmaf(w, mv.z, acc.z);
      acc.w = fmaf(w, mv.w, acc.w);
    }
  }
  ((float4*)part)[((size_t)s * BB + b) * (EMBD / 4) + tid] = acc;
}

// ---------------- K5: reduce partials -> context
__global__ void k_ctx_reduce(const float* __restrict__ part,
                             float* __restrict__ ctx) {
  const int j = blockIdx.x * 256 + threadIdx.x;   // < B*EMB/4 = 16384
  const float4* p4 = (const float4*)part;
  float4 acc = p4[j];
  #pragma unroll
  for (int s = 1; s < SPLIT; ++s) {
    const float4 v = p4[(size_t)s * (BB * EMBD / 4) + j];
    acc.x += v.x; acc.y += v.y; acc.z += v.z; acc.w += v.w;
  }
  ((float4*)ctx)[j] = acc;
}

extern "C" void kernel_launch(void* const* d_in, const int* in_sizes, int n_in,
                              void* d_out, int out_size, void* d_ws, size_t ws_size,
                              hipStream_t stream) {
  const float* hid   = (const float*)d_in[0];   // [B, RNN]
  const float* mem   = (const float*)d_in[1];   // [B, T, EMB]
  const float* pmem  = (const float*)d_in[2];   // [B, T, ATT]
  const float* awc   = (const float*)d_in[3];   // [B, 2, T]
  const unsigned char* mask = (const unsigned char*)d_in[4]; // [B, T] bool
  const float* wq    = (const float*)d_in[5];   // [RNN, ATT]
  const float* wconv = (const float*)d_in[6];   // [NF, 2, K]
  const float* wloc  = (const float*)d_in[7];   // [NF, ATT]
  const float* v     = (const float*)d_in[8];   // [ATT]

  float* out = (float*)d_out;
  float* ctx = out;                 // [B, EMB]   (output 0)
  float* wts = out + BB * EMBD;     // [B, T]     (output 1; also energies scratch)

  char* ws = (char*)d_ws;
  float* pq   = (float*)(ws);               // B*ATT*4       = 64 KB
  float* wl   = (float*)(ws + 65536);       // 62*128*4      = 31.75 KB
  float* part = (float*)(ws + (1 << 20));   // SPLIT*B*EMB*4 = 4 MB

  k_pq_wl<<<BB + 31, 256, 0, stream>>>(hid, wq, wconv, wloc, pq, wl);
  k_energy<<<dim3(BB, TT / ETILE), 256, 0, stream>>>(awc, pmem, wl, v, pq, mask, wts);
  k_softmax<<<BB, 256, 0, stream>>>(wts);
  k_ctx_part<<<dim3(BB, SPLIT), 128, 0, stream>>>(wts, mem, part);
  k_ctx_reduce<<<64, 256, 0, stream>>>(part, ctx);
}

// Round 5
// 498.715 us; speedup vs baseline: 1.0217x; 1.0217x over previous
//
#include <hip/hip_runtime.h>
#include <math.h>

#define BB    128
#define TT    1024
#define RNN   1024
#define EMBD  512
#define ATTD  128
#define NFILT 32
#define KSZ   31
#define PADK  15
#define CK    62        // 2 * 31
#define SPLIT 16
#define TSP   (TT / SPLIT)   // 64 timesteps per split

// fast tanh: t = exp(-2|x|); r = (1-t)/(1+t); sign-restore.
// |err| ~ 1e-6 absolute, saturates correctly, no overflow/NaN for any finite x.
__device__ __forceinline__ float fast_tanhf(float x) {
  const float ax = fabsf(x);
  const float t  = __expf(-2.f * ax);
  const float r  = (1.f - t) / (1.f + t);
  return copysignf(r, x);
}

// ---------------- K1 (fused): blocks [0,128) -> pq = hidden @ w_query
//                              blocks [128,159) -> WL[ck][a] = sum_f wconv[f][ck]*wloc[f][a]
__global__ __launch_bounds__(256) void k_pq_wl(const float* __restrict__ hid,
                                               const float* __restrict__ wq,
                                               const float* __restrict__ wconv,
                                               const float* __restrict__ wloc,
                                               float* __restrict__ pq,
                                               float* __restrict__ wl) {
  const int tid = threadIdx.x;
  if (blockIdx.x < BB) {
    const int b  = blockIdx.x;
    const int a  = tid & (ATTD - 1);
    const int kh = tid >> 7;                 // split-K half: 0 or 1
    __shared__ float sh[RNN];
    __shared__ float sred[ATTD];
    for (int i = tid; i < RNN; i += 256) sh[i] = hid[(size_t)b * RNN + i];
    __syncthreads();
    float acc = 0.f;
    const int k0 = kh * (RNN / 2);
    #pragma unroll 8
    for (int k = 0; k < RNN / 2; ++k)
      acc = fmaf(sh[k0 + k], wq[(size_t)(k0 + k) * ATTD + a], acc);
    if (kh == 1) sred[a] = acc;
    __syncthreads();
    if (kh == 0) pq[(size_t)b * ATTD + a] = acc + sred[a];
  } else {
    const int idx = (blockIdx.x - BB) * 256 + tid;   // 31*256 == 7936 == CK*ATTD
    const int ck = idx >> 7;
    const int a  = idx & (ATTD - 1);
    float acc = 0.f;
    #pragma unroll
    for (int f = 0; f < NFILT; ++f)
      acc = fmaf(wconv[f * CK + ck], wloc[f * ATTD + a], acc);
    wl[idx] = acc;
  }
}

// ---------------- K2: fused energies + split-softmax + ctx partial.
// One block per (b, split of 64 t's). 128 threads = 2 waves.
// Phase 1: energies (wave handles t, lanes hold a-pairs)
// Phase 2: per-split softmax partial (m_s, sum_s), p_t = exp(e - m_s)
// Phase 3: ctx_s[512] += p_t * mem[b,t,:]  (thread owns 4 emb components)
__global__ __launch_bounds__(128, 3) void k_fused(
    const float* __restrict__ awc,   // [B,2,T]
    const float* __restrict__ pmem,  // [B,T,128]
    const float* __restrict__ mem,   // [B,T,512]
    const float* __restrict__ wl,    // [62,128]
    const float* __restrict__ vvec,  // [128]
    const float* __restrict__ pq,    // [B,128]
    const unsigned char* __restrict__ mask, // [B,T]
    float* __restrict__ wts,         // [B,T]  (unnormalized p, fixed by combine)
    float* __restrict__ part_ctx,    // [SPLIT*B*512]
    float* __restrict__ part_ms,     // [SPLIT*B]
    float* __restrict__ part_sum)    // [SPLIT*B]
{
  const int blk  = blockIdx.x;
  const int b    = blk & (BB - 1);
  const int s    = blk >> 7;
  const int tid  = threadIdx.x;
  const int lane = tid & 63;
  const int wave = tid >> 6;
  const int t0   = s * TSP;

  __shared__ float s_aw[2][TSP + 30];
  __shared__ float s_p[TSP];

  // stage attention_weights_cat halo, zero-padded at borders
  for (int i = tid; i < 2 * (TSP + 30); i += 128) {
    const int c  = (i >= TSP + 30);
    const int j  = c ? i - (TSP + 30) : i;
    const int tg = t0 - PADK + j;
    s_aw[c][j] = (tg >= 0 && tg < TT) ? awc[((size_t)b * 2 + c) * TT + tg] : 0.f;
  }

  // lane-resident operands (128 a-components as 64 lane-pairs)
  float2 wlr[CK];
  const float2* wl2 = (const float2*)wl;
  #pragma unroll
  for (int ck = 0; ck < CK; ++ck) wlr[ck] = wl2[ck * 64 + lane];
  const float2 pq2 = ((const float2*)(pq + (size_t)b * ATTD))[lane];
  const float2 v2  = ((const float2*)vvec)[lane];
  const float2* pm2 = (const float2*)(pmem + (size_t)b * TT * ATTD);
  __syncthreads();

  // ---- phase 1: energies, 2 waves x 32 t's
  for (int i = 0; i < TSP / 2; ++i) {
    const int tl = wave * (TSP / 2) + i;
    const int tg = t0 + tl;
    const float2 pm = pm2[(size_t)tg * 64 + lane];
    float x0 = pq2.x + pm.x;
    float x1 = pq2.y + pm.y;
    #pragma unroll
    for (int k = 0; k < KSZ; ++k) {          // channel 0
      const float a0 = s_aw[0][tl + k];
      x0 = fmaf(a0, wlr[k].x, x0);
      x1 = fmaf(a0, wlr[k].y, x1);
    }
    #pragma unroll
    for (int k = 0; k < KSZ; ++k) {          // channel 1
      const float a1 = s_aw[1][tl + k];
      x0 = fmaf(a1, wlr[KSZ + k].x, x0);
      x1 = fmaf(a1, wlr[KSZ + k].y, x1);
    }
    float e = v2.x * fast_tanhf(x0) + v2.y * fast_tanhf(x1);
    #pragma unroll
    for (int off = 32; off; off >>= 1) e += __shfl_xor(e, off);
    if (lane == 0) s_p[tl] = e;
  }
  __syncthreads();

  // ---- phase 2: split-softmax partial (wave 0 only; 64 lanes = 64 t's)
  if (wave == 0) {
    float e = s_p[lane];
    if (mask[(size_t)b * TT + t0 + lane]) e = -INFINITY;
    float m = e;
    #pragma unroll
    for (int off = 32; off; off >>= 1) m = fmaxf(m, __shfl_xor(m, off));
    const float p = __expf(e - m);
    float sum = p;
    #pragma unroll
    for (int off = 32; off; off >>= 1) sum += __shfl_xor(sum, off);
    s_p[lane] = p;
    wts[(size_t)b * TT + t0 + lane] = p;
    if (lane == 0) {
      part_ms [(size_t)s * BB + b] = m;
      part_sum[(size_t)s * BB + b] = sum;
    }
  }
  __syncthreads();

  // ---- phase 3: ctx partial over the 64-t slab (the 256 MB stream)
  const float4* m4 = (const float4*)(mem + (size_t)b * TT * EMBD) + (size_t)t0 * (EMBD / 4);
  float4 acc = make_float4(0.f, 0.f, 0.f, 0.f);
  #pragma unroll 8
  for (int t = 0; t < TSP; ++t) {
    const float p  = s_p[t];                       // LDS broadcast
    const float4 mv = m4[(size_t)t * (EMBD / 4) + tid];
    acc.x = fmaf(p, mv.x, acc.x);
    acc.y = fmaf(p, mv.y, acc.y);
    acc.z = fmaf(p, mv.z, acc.z);
    acc.w = fmaf(p, mv.w, acc.w);
  }
  ((float4*)part_ctx)[((size_t)s * BB + b) * (EMBD / 4) + tid] = acc;
}

// ---------------- K3: combine splits -> ctx + normalized weights
__global__ __launch_bounds__(128) void k_combine(
    const float* __restrict__ part_ctx,
    const float* __restrict__ part_ms,
    const float* __restrict__ part_sum,
    float* __restrict__ ctx,         // [B,512]
    float* __restrict__ wts)         // [B,T] in/out
{
  const int b   = blockIdx.x;
  const int tid = threadIdx.x;
  __shared__ float s_a[SPLIT];       // alpha_s / T

  float M = -INFINITY;
  #pragma unroll
  for (int s = 0; s < SPLIT; ++s) M = fmaxf(M, part_ms[(size_t)s * BB + b]);
  float T = 0.f;
  #pragma unroll
  for (int s = 0; s < SPLIT; ++s)
    T += part_sum[(size_t)s * BB + b] * __expf(part_ms[(size_t)s * BB + b] - M);
  const float invT = 1.f / T;
  if (tid < SPLIT) s_a[tid] = __expf(part_ms[(size_t)tid * BB + b] - M) * invT;
  __syncthreads();

  // ctx = sum_s (alpha_s/T) * ctx_s   (thread owns 4 emb components)
  float4 acc = make_float4(0.f, 0.f, 0.f, 0.f);
  #pragma unroll
  for (int s = 0; s < SPLIT; ++s) {
    const float a = s_a[s];
    const float4 v = ((const float4*)part_ctx)[((size_t)s * BB + b) * (EMBD / 4) + tid];
    acc.x = fmaf(a, v.x, acc.x);
    acc.y = fmaf(a, v.y, acc.y);
    acc.z = fmaf(a, v.z, acc.z);
    acc.w = fmaf(a, v.w, acc.w);
  }
  ((float4*)ctx)[(size_t)b * (EMBD / 4) + tid] = acc;

  // normalize weights: w_t *= alpha_{s(t)}/T ; t = i*128+tid keeps s wave-uniform
  #pragma unroll
  for (int i = 0; i < TT / 128; ++i) {
    const int t = i * 128 + tid;
    wts[(size_t)b * TT + t] *= s_a[t >> 6];
  }
}

extern "C" void kernel_launch(void* const* d_in, const int* in_sizes, int n_in,
                              void* d_out, int out_size, void* d_ws, size_t ws_size,
                              hipStream_t stream) {
  const float* hid   = (const float*)d_in[0];   // [B, RNN]
  const float* mem   = (const float*)d_in[1];   // [B, T, EMB]
  const float* pmem  = (const float*)d_in[2];   // [B, T, ATT]
  const float* awc   = (const float*)d_in[3];   // [B, 2, T]
  const unsigned char* mask = (const unsigned char*)d_in[4]; // [B, T] bool
  const float* wq    = (const float*)d_in[5];   // [RNN, ATT]
  const float* wconv = (const float*)d_in[6];   // [NF, 2, K]
  const float* wloc  = (const float*)d_in[7];   // [NF, ATT]
  const float* v     = (const float*)d_in[8];   // [ATT]

  float* out = (float*)d_out;
  float* ctx = out;                 // [B, EMB]   (output 0)
  float* wts = out + BB * EMBD;     // [B, T]     (output 1)

  char* ws = (char*)d_ws;
  float* pq       = (float*)(ws);                // 64 KB
  float* wl       = (float*)(ws + (64 << 10));   // 31.75 KB
  float* part_ms  = (float*)(ws + (128 << 10));  // SPLIT*B*4 = 8 KB
  float* part_sum = (float*)(ws + (192 << 10));  // 8 KB
  float* part_ctx = (float*)(ws + (1 << 20));    // SPLIT*B*EMB*4 = 4 MB

  k_pq_wl<<<BB + 31, 256, 0, stream>>>(hid, wq, wconv, wloc, pq, wl);
  k_fused<<<SPLIT * BB, 128, 0, stream>>>(awc, pmem, mem, wl, v, pq, mask,
                                          wts, part_ctx, part_ms, part_sum);
  k_combine<<<BB, 128, 0, stream>>>(part_ctx, part_ms, part_sum, ctx, wts);
}

// Round 6
// 470.262 us; speedup vs baseline: 1.0836x; 1.0605x over previous
//
#include <hip/hip_runtime.h>
#include <math.h>

#define BB    128
#define TT    1024
#define RNN   1024
#define EMBD  512
#define ATTD  128
#define NFILT 32
#define KSZ   31
#define PADK  15
#define CK    62        // 2 * 31
#define SPLIT 32
#define TSP   (TT / SPLIT)   // 32 timesteps per split

// fast tanh: t = exp(-2|x|); r = (1-t)/(1+t); sign-restore.
__device__ __forceinline__ float fast_tanhf(float x) {
  const float ax = fabsf(x);
  const float t  = __expf(-2.f * ax);
  const float r  = (1.f - t) / (1.f + t);
  return copysignf(r, x);
}

// ---------------- K1 (fused): blocks [0,128) -> pq = hidden @ w_query
//                              blocks [128,159) -> WL[ck][a] = sum_f wconv[f][ck]*wloc[f][a]
__global__ __launch_bounds__(256) void k_pq_wl(const float* __restrict__ hid,
                                               const float* __restrict__ wq,
                                               const float* __restrict__ wconv,
                                               const float* __restrict__ wloc,
                                               float* __restrict__ pq,
                                               float* __restrict__ wl) {
  const int tid = threadIdx.x;
  if (blockIdx.x < BB) {
    const int b  = blockIdx.x;
    const int a  = tid & (ATTD - 1);
    const int kh = tid >> 7;                 // split-K half: 0 or 1
    __shared__ float sh[RNN];
    __shared__ float sred[ATTD];
    for (int i = tid; i < RNN; i += 256) sh[i] = hid[(size_t)b * RNN + i];
    __syncthreads();
    float acc = 0.f;
    const int k0 = kh * (RNN / 2);
    #pragma unroll 8
    for (int k = 0; k < RNN / 2; ++k)
      acc = fmaf(sh[k0 + k], wq[(size_t)(k0 + k) * ATTD + a], acc);
    if (kh == 1) sred[a] = acc;
    __syncthreads();
    if (kh == 0) pq[(size_t)b * ATTD + a] = acc + sred[a];
  } else {
    const int idx = (blockIdx.x - BB) * 256 + tid;   // 31*256 == 7936 == CK*ATTD
    const int ck = idx >> 7;
    const int a  = idx & (ATTD - 1);
    float acc = 0.f;
    #pragma unroll
    for (int f = 0; f < NFILT; ++f)
      acc = fmaf(wconv[f * CK + ck], wloc[f * ATTD + a], acc);
    wl[idx] = acc;
  }
}

// ---------------- K2: fused energies + split-softmax + ctx partial.
// One block per (b, split of 32 t's). 256 threads = 4 waves.
// a-dim split across wave pairs: wave owns 64 a-components -> wlr is 62
// SCALAR floats (62 VGPR, register-resident; round-5's float2[62]=124 regs
// forced the compiler to re-read wl from L2 every t -> 4 GB L2 traffic).
// waves {0,1}: t 0..15 (a-half 0 / 1);  waves {2,3}: t 16..31.
__global__ __launch_bounds__(256, 4) void k_fused(
    const float* __restrict__ awc,   // [B,2,T]
    const float* __restrict__ pmem,  // [B,T,128]
    const float* __restrict__ mem,   // [B,T,512]
    const float* __restrict__ wl,    // [62,128]
    const float* __restrict__ vvec,  // [128]
    const float* __restrict__ pq,    // [B,128]
    const unsigned char* __restrict__ mask, // [B,T]
    float* __restrict__ wts,         // [B,T]  (unnormalized p, fixed by combine)
    float* __restrict__ part_ctx,    // [SPLIT*B*512]
    float* __restrict__ part_ms,     // [SPLIT*B]
    float* __restrict__ part_sum)    // [SPLIT*B]
{
  const int blk  = blockIdx.x;
  const int b    = blk & (BB - 1);
  const int s    = blk >> 7;
  const int tid  = threadIdx.x;
  const int lane = tid & 63;
  const int wave = tid >> 6;           // 0..3
  const int t0   = s * TSP;

  __shared__ float s_aw[2][TSP + 30];  // 2 x 62 halo-staged conv inputs
  __shared__ float s_e[TSP][2];        // per-t energy partials (a-halves)
  __shared__ float s_p[TSP];           // per-t unnormalized softmax p

  // stage attention_weights_cat halo, zero-padded at borders
  for (int i = tid; i < 2 * (TSP + 30); i += 256) {
    const int c  = (i >= TSP + 30);
    const int j  = c ? i - (TSP + 30) : i;
    const int tg = t0 - PADK + j;
    s_aw[c][j] = (tg >= 0 && tg < TT) ? awc[((size_t)b * 2 + c) * TT + tg] : 0.f;
  }

  // wave's a-component: scalar per lane
  const int a = ((wave & 1) << 6) + lane;
  float wlr[CK];
  #pragma unroll
  for (int ck = 0; ck < CK; ++ck) wlr[ck] = wl[ck * ATTD + a];
  const float pqv = pq[(size_t)b * ATTD + a];
  const float vv  = vvec[a];
  const float* pmb = pmem + (size_t)b * TT * ATTD;
  __syncthreads();

  // ---- phase 1: energies. wave-pair covers 16 t's; two FMA chains for ILP.
  const int tg0 = (wave >> 1) * (TSP / 2);
  float pm_next = pmb[(size_t)(t0 + tg0) * ATTD + a];
  for (int i = 0; i < TSP / 2; ++i) {
    const int tl = tg0 + i;
    const float pm = pm_next;
    if (i + 1 < TSP / 2) pm_next = pmb[(size_t)(t0 + tl + 1) * ATTD + a];
    float x0 = pqv + pm;
    float x1 = 0.f;
    #pragma unroll
    for (int k = 0; k < KSZ; ++k) {
      x0 = fmaf(s_aw[0][tl + k], wlr[k], x0);         // channel 0 chain
      x1 = fmaf(s_aw[1][tl + k], wlr[KSZ + k], x1);   // channel 1 chain
    }
    float pe = vv * fast_tanhf(x0 + x1);
    #pragma unroll
    for (int off = 32; off; off >>= 1) pe += __shfl_xor(pe, off);
    if (lane == 0) s_e[tl][wave & 1] = pe;
  }
  __syncthreads();

  // ---- phase 2: split-softmax partial (wave 0; lanes 0..31 hold t's)
  if (wave == 0) {
    float e = -INFINITY;
    if (lane < TSP) {
      e = s_e[lane][0] + s_e[lane][1];
      if (mask[(size_t)b * TT + t0 + lane]) e = -INFINITY;
    }
    float m = e;
    #pragma unroll
    for (int off = 32; off; off >>= 1) m = fmaxf(m, __shfl_xor(m, off));
    const float p = (lane < TSP) ? __expf(e - m) : 0.f;
    float sum = p;
    #pragma unroll
    for (int off = 32; off; off >>= 1) sum += __shfl_xor(sum, off);
    if (lane < TSP) {
      s_p[lane] = p;
      wts[(size_t)b * TT + t0 + lane] = p;
    }
    if (lane == 0) {
      part_ms [(size_t)s * BB + b] = m;
      part_sum[(size_t)s * BB + b] = sum;
    }
  }
  __syncthreads();

  // ---- phase 3: ctx partial over the 32-t slab (the 256 MB stream).
  // thread owns one float2 of the 512 emb components.
  const float2* m2 = (const float2*)(mem + ((size_t)b * TT + t0) * EMBD);
  float2 acc = make_float2(0.f, 0.f);
  #pragma unroll 8
  for (int t = 0; t < TSP; ++t) {
    const float p   = s_p[t];                     // LDS broadcast
    const float2 mv = m2[(size_t)t * (EMBD / 2) + tid];
    acc.x = fmaf(p, mv.x, acc.x);
    acc.y = fmaf(p, mv.y, acc.y);
  }
  ((float2*)part_ctx)[((size_t)s * BB + b) * (EMBD / 2) + tid] = acc;
}

// ---------------- K3: combine splits -> ctx + normalized weights
__global__ __launch_bounds__(128) void k_combine(
    const float* __restrict__ part_ctx,
    const float* __restrict__ part_ms,
    const float* __restrict__ part_sum,
    float* __restrict__ ctx,         // [B,512]
    float* __restrict__ wts)         // [B,T] in/out
{
  const int b   = blockIdx.x;
  const int tid = threadIdx.x;
  __shared__ float s_a[SPLIT];       // alpha_s / T

  float M = -INFINITY;
  #pragma unroll
  for (int s = 0; s < SPLIT; ++s) M = fmaxf(M, part_ms[(size_t)s * BB + b]);
  float T = 0.f;
  #pragma unroll
  for (int s = 0; s < SPLIT; ++s)
    T += part_sum[(size_t)s * BB + b] * __expf(part_ms[(size_t)s * BB + b] - M);
  const float invT = 1.f / T;
  if (tid < SPLIT) s_a[tid] = __expf(part_ms[(size_t)tid * BB + b] - M) * invT;
  __syncthreads();

  // ctx = sum_s (alpha_s/T) * ctx_s   (thread owns 4 emb components)
  float4 acc = make_float4(0.f, 0.f, 0.f, 0.f);
  #pragma unroll
  for (int s = 0; s < SPLIT; ++s) {
    const float a = s_a[s];
    const float4 v = ((const float4*)part_ctx)[((size_t)s * BB + b) * (EMBD / 4) + tid];
    acc.x = fmaf(a, v.x, acc.x);
    acc.y = fmaf(a, v.y, acc.y);
    acc.z = fmaf(a, v.z, acc.z);
    acc.w = fmaf(a, v.w, acc.w);
  }
  ((float4*)ctx)[(size_t)b * (EMBD / 4) + tid] = acc;

  // normalize weights: w_t *= alpha_{s(t)}/T
  #pragma unroll
  for (int i = 0; i < TT / 128; ++i) {
    const int t = i * 128 + tid;
    wts[(size_t)b * TT + t] *= s_a[t / TSP];
  }
}

extern "C" void kernel_launch(void* const* d_in, const int* in_sizes, int n_in,
                              void* d_out, int out_size, void* d_ws, size_t ws_size,
                              hipStream_t stream) {
  const float* hid   = (const float*)d_in[0];   // [B, RNN]
  const float* mem   = (const float*)d_in[1];   // [B, T, EMB]
  const float* pmem  = (const float*)d_in[2];   // [B, T, ATT]
  const float* awc   = (const float*)d_in[3];   // [B, 2, T]
  const unsigned char* mask = (const unsigned char*)d_in[4]; // [B, T] bool
  const float* wq    = (const float*)d_in[5];   // [RNN, ATT]
  const float* wconv = (const float*)d_in[6];   // [NF, 2, K]
  const float* wloc  = (const float*)d_in[7];   // [NF, ATT]
  const float* v     = (const float*)d_in[8];   // [ATT]

  float* out = (float*)d_out;
  float* ctx = out;                 // [B, EMB]   (output 0)
  float* wts = out + BB * EMBD;     // [B, T]     (output 1)

  char* ws = (char*)d_ws;
  float* pq       = (float*)(ws);                // 64 KB
  float* wl       = (float*)(ws + (64 << 10));   // 31.75 KB
  float* part_ms  = (float*)(ws + (128 << 10));  // SPLIT*B*4 = 16 KB
  float* part_sum = (float*)(ws + (256 << 10));  // 16 KB
  float* part_ctx = (float*)(ws + (1 << 20));    // SPLIT*B*EMB*4 = 8 MB

  k_pq_wl<<<BB + 31, 256, 0, stream>>>(hid, wq, wconv, wloc, pq, wl);
  k_fused<<<SPLIT * BB, 256, 0, stream>>>(awc, pmem, mem, wl, v, pq, mask,
                                          wts, part_ctx, part_ms, part_sum);
  k_combine<<<BB, 128, 0, stream>>>(part_ctx, part_ms, part_sum, ctx, wts);
}